// Round 5
// baseline (332.016 us; speedup 1.0000x reference)
//
#include <hip/hip_runtime.h>
#include <math.h>

#define F_DIM 64
#define K_CL 16
#define B_GR 16

typedef _Float16 h16;
using f16x8 = __attribute__((ext_vector_type(8))) _Float16;
using f32x4 = __attribute__((ext_vector_type(4))) float;

// ---------------------------------------------------------------------------
// K1: s = x@W + b ; ss = softmax(s) (fp32 + f16 copy). One thread per node.
// ---------------------------------------------------------------------------
__global__ __launch_bounds__(256) void k_assign(
    const float* __restrict__ x, const float* __restrict__ W, const float* __restrict__ bvec,
    float* __restrict__ ss, float* __restrict__ sraw, h16* __restrict__ ssh)
{
    __shared__ float Wl[F_DIM * K_CL];
    __shared__ float bl[K_CL];
    int t = threadIdx.x;
    for (int idx = t; idx < F_DIM * K_CL; idx += 256) Wl[idx] = W[idx];
    if (t < K_CL) bl[t] = bvec[t];
    __syncthreads();

    size_t i = (size_t)blockIdx.x * 256 + t;
    float s[K_CL];
#pragma unroll
    for (int k = 0; k < 16; ++k) s[k] = bl[k];

    const float4* xp = reinterpret_cast<const float4*>(x + i * F_DIM);
#pragma unroll
    for (int j = 0; j < 16; ++j) {
        float4 q = xp[j];
        float xf[4] = {q.x, q.y, q.z, q.w};
#pragma unroll
        for (int ff = 0; ff < 4; ++ff) {
            int f = j * 4 + ff;
            float xv = xf[ff];
            const float4* wr = reinterpret_cast<const float4*>(&Wl[f * K_CL]);
            float4 w0 = wr[0], w1 = wr[1], w2 = wr[2], w3 = wr[3];
            s[0]  += xv * w0.x; s[1]  += xv * w0.y; s[2]  += xv * w0.z; s[3]  += xv * w0.w;
            s[4]  += xv * w1.x; s[5]  += xv * w1.y; s[6]  += xv * w1.z; s[7]  += xv * w1.w;
            s[8]  += xv * w2.x; s[9]  += xv * w2.y; s[10] += xv * w2.z; s[11] += xv * w2.w;
            s[12] += xv * w3.x; s[13] += xv * w3.y; s[14] += xv * w3.z; s[15] += xv * w3.w;
        }
    }

    float4* sp = reinterpret_cast<float4*>(sraw + i * K_CL);
    sp[0] = make_float4(s[0], s[1], s[2], s[3]);
    sp[1] = make_float4(s[4], s[5], s[6], s[7]);
    sp[2] = make_float4(s[8], s[9], s[10], s[11]);
    sp[3] = make_float4(s[12], s[13], s[14], s[15]);

    float m = s[0];
#pragma unroll
    for (int k = 1; k < 16; ++k) m = fmaxf(m, s[k]);
    float sum = 0.f;
#pragma unroll
    for (int k = 0; k < 16; ++k) { s[k] = __expf(s[k] - m); sum += s[k]; }
    float inv = 1.0f / sum;
#pragma unroll
    for (int k = 0; k < 16; ++k) s[k] *= inv;

    float4* qp = reinterpret_cast<float4*>(ss + i * K_CL);
    qp[0] = make_float4(s[0], s[1], s[2], s[3]);
    qp[1] = make_float4(s[4], s[5], s[6], s[7]);
    qp[2] = make_float4(s[8], s[9], s[10], s[11]);
    qp[3] = make_float4(s[12], s[13], s[14], s[15]);

    f16x8 h0, h1;
#pragma unroll
    for (int k = 0; k < 8; ++k) { h0[k] = (h16)s[k]; h1[k] = (h16)s[k + 8]; }
    f16x8* hp = reinterpret_cast<f16x8*>(ssh + i * K_CL);
    hp[0] = h0;
    hp[1] = h1;
}

// ---------------------------------------------------------------------------
// K2: oadj[k,l] = sum_e (w*ss[r,k])*ss[c,l] via MFMA 16x16x32_f16, K=edges.
// Per 64 edges: 3 coalesced edge loads, shfl broadcast, 2-byte gathers
// (coalesced per 16-lane group), 2 MFMAs, fp32 accum.
// D layout col=lane&15,row=quad*4+reg covers all 256 cells -> no butterfly.
// ---------------------------------------------------------------------------
__global__ __launch_bounds__(256) void k_edge(
    const int* __restrict__ erow, const int* __restrict__ ecol, const float* __restrict__ ew,
    const h16* __restrict__ ssh, float* __restrict__ padj,
    int edges_per_block, int edges_per_graph, int nmask)
{
    __shared__ float CCl[256];
    int t = threadIdx.x;
    CCl[t] = 0.f;
    __syncthreads();

    int bid = blockIdx.x;
    int xcd = bid & 7;
    int slot = bid >> 3;                       // 0..255
    int graph = xcd + 8 * (slot & 1);
    int chunk = slot >> 1;                     // 0..127

    int wid = t >> 6, lane = t & 63;
    int quad = lane >> 4, m = lane & 15;

    int epw = edges_per_block >> 2;            // 512
    size_t base = (size_t)graph * edges_per_graph
                + (size_t)chunk * edges_per_block
                + (size_t)wid * epw;

    f32x4 acc = {0.f, 0.f, 0.f, 0.f};

    for (int e0 = 0; e0 < epw; e0 += 64) {
        size_t eb = base + e0 + lane;
        int   rv = erow[eb] & nmask;
        int   cv = ecol[eb] & nmask;
        float wv = ew[eb];
#pragma unroll
        for (int h = 0; h < 2; ++h) {
            f16x8 afrag, bfrag;
#pragma unroll
            for (int j = 0; j < 8; ++j) {
                int src = h * 32 + quad * 8 + j;
                int   r = __shfl(rv, src, 64);
                int   c = __shfl(cv, src, 64);
                float w = __shfl(wv, src, 64);
                h16 av = ssh[(size_t)r * 16 + m];
                h16 bv = ssh[(size_t)c * 16 + m];
                afrag[j] = av * (h16)w;
                bfrag[j] = bv;
            }
            acc = __builtin_amdgcn_mfma_f32_16x16x32_f16(afrag, bfrag, acc, 0, 0, 0);
        }
    }

#pragma unroll
    for (int rg = 0; rg < 4; ++rg)
        atomicAdd(&CCl[(quad * 4 + rg) * 16 + m], acc[rg]);
    __syncthreads();
    padj[(size_t)bid * 256 + t] = CCl[t];
}

// ---------------------------------------------------------------------------
// K3: per-node pass: outx[g,k,f], CC[g]=ss^T ss, cs[g,k]. Partial stores.
// ---------------------------------------------------------------------------
__global__ __launch_bounds__(256) void k_nodes(
    const float* __restrict__ x, const float* __restrict__ sraw, const float* __restrict__ ss,
    float* __restrict__ poutx, float* __restrict__ pCC, float* __restrict__ pcs,
    int npw)
{
    __shared__ float redx[4 * K_CL * F_DIM];   // 16 KB
    __shared__ float CCl[256];
    __shared__ float csl[16];
    int t = threadIdx.x;
    CCl[t] = 0.f;
    if (t < 16) csl[t] = 0.f;
    __syncthreads();

    int wid = t >> 6, lane = t & 63;
    int g4 = lane >> 4, l = lane & 15;
    size_t base = ((size_t)blockIdx.x * 4 + wid) * npw;

    float accx[16];
#pragma unroll
    for (int k = 0; k < 16; ++k) accx[k] = 0.f;
    float accc[4] = {0.f, 0.f, 0.f, 0.f};
    float acccs = 0.f;

    for (int j = 0; j < npw; ++j) {
        size_t i = base + j;
        float xv = x[i * F_DIM + lane];
        const float4* sp = reinterpret_cast<const float4*>(sraw + i * K_CL);
        float4 s0 = sp[0], s1 = sp[1], s2 = sp[2], s3 = sp[3];
        accx[0]  += s0.x * xv; accx[1]  += s0.y * xv; accx[2]  += s0.z * xv; accx[3]  += s0.w * xv;
        accx[4]  += s1.x * xv; accx[5]  += s1.y * xv; accx[6]  += s1.z * xv; accx[7]  += s1.w * xv;
        accx[8]  += s2.x * xv; accx[9]  += s2.y * xv; accx[10] += s2.z * xv; accx[11] += s2.w * xv;
        accx[12] += s3.x * xv; accx[13] += s3.y * xv; accx[14] += s3.z * xv; accx[15] += s3.w * xv;

        float sv = ss[i * K_CL + l];
        accc[0] += __shfl(sv, g4 * 4 + 0, 16) * sv;
        accc[1] += __shfl(sv, g4 * 4 + 1, 16) * sv;
        accc[2] += __shfl(sv, g4 * 4 + 2, 16) * sv;
        accc[3] += __shfl(sv, g4 * 4 + 3, 16) * sv;
        acccs += sv;
    }

#pragma unroll
    for (int k = 0; k < 16; ++k) redx[wid * 1024 + k * 64 + lane] = accx[k];
#pragma unroll
    for (int j4 = 0; j4 < 4; ++j4)
        atomicAdd(&CCl[(g4 * 4 + j4) * 16 + l], accc[j4]);
    if (g4 == 0) atomicAdd(&csl[l], acccs);
    __syncthreads();

    int bid = blockIdx.x;
    for (int idx = t; idx < K_CL * F_DIM; idx += 256) {
        float v = redx[idx] + redx[1024 + idx] + redx[2048 + idx] + redx[3072 + idx];
        poutx[(size_t)bid * 1024 + idx] = v;
    }
    pCC[(size_t)bid * 256 + t] = CCl[t];
    if (t < 16) pcs[(size_t)bid * 16 + t] = csl[t];
}

// ---------------------------------------------------------------------------
// K4: reduce partials (one block per graph) + fused selu epilogue for out_x.
// ---------------------------------------------------------------------------
__global__ __launch_bounds__(256) void k_reduce(
    const float* __restrict__ padj, const float* __restrict__ poutx,
    const float* __restrict__ pCC, const float* __restrict__ pcs,
    float* __restrict__ oadj, float* __restrict__ CCb, float* __restrict__ csb,
    float* __restrict__ out, int adj_slots, int node_slots)
{
    int g = blockIdx.x, t = threadIdx.x;

    float s = 0.f;
    for (int i = 0; i < adj_slots; ++i)
        s += padj[((size_t)g * adj_slots + i) * 256 + t];
    oadj[g * 256 + t] = s;

    float c = 0.f;
    for (int i = 0; i < node_slots; ++i)
        c += pCC[((size_t)g * node_slots + i) * 256 + t];
    CCb[g * 256 + t] = c;

    if (t < 16) {
        float cs = 0.f;
        for (int i = 0; i < node_slots; ++i)
            cs += pcs[((size_t)g * node_slots + i) * 16 + t];
        csb[g * 16 + t] = cs;
    }

    for (int idx = t; idx < K_CL * F_DIM; idx += 256) {
        float v = 0.f;
        for (int i = 0; i < node_slots; ++i)
            v += poutx[((size_t)g * node_slots + i) * 1024 + idx];
        float r = (v > 0.f) ? (1.0507009873554805f * v)
                            : (1.0507009873554805f * 1.6732632423543772f * (__expf(v) - 1.0f));
        out[g * 1024 + idx] = r;
    }
}

// ---------------------------------------------------------------------------
// K5: finalize losses + out_adj_norm. dS = column sums of oadj, m2 = total
// sum (softmax rows sum to 1 -> degree vector algebraically redundant).
// ---------------------------------------------------------------------------
__global__ __launch_bounds__(256) void k_final(
    const float* __restrict__ oadj, const float* __restrict__ CCb,
    const float* __restrict__ csb, float* __restrict__ out, int npg)
{
    int t = threadIdx.x;
    int b = t >> 4, k = t & 15;
    const float* oar = oadj + b * 256 + k * 16;
    const float* ccr = CCb + b * 256 + k * 16;

    float rowsum_off = 0.f, trace_c = 0.f, rowsum_all = 0.f, fro2 = 0.f, colsum = 0.f;
#pragma unroll
    for (int l = 0; l < 16; ++l) {
        float v = oar[l];
        rowsum_all += v;
        if (l == k) trace_c = v; else rowsum_off += v;
        float c = ccr[l];
        fro2 += c * c;
        colsum += oadj[b * 256 + l * 16 + k];
    }
    float dd = sqrtf(rowsum_off) + 1e-12f;
    __shared__ float ddl[B_GR * K_CL];
    ddl[t] = dd;

    float csv = csb[t];
    float ds2 = colsum * colsum, cs2 = csv * csv;
    float tr = trace_c, m2 = rowsum_all;
#pragma unroll
    for (int msk = 8; msk >= 1; msk >>= 1) {
        tr   += __shfl_xor(tr,   msk, 16);
        ds2  += __shfl_xor(ds2,  msk, 16);
        cs2  += __shfl_xor(cs2,  msk, 16);
        fro2 += __shfl_xor(fro2, msk, 16);
        m2   += __shfl_xor(m2,   msk, 16);
    }
    float invfro = 1.0f / sqrtf(fro2);
    float osum = 0.f;
#pragma unroll
    for (int l = 0; l < 16; ++l) {
        float v = ccr[l] * invfro - ((l == k) ? 0.25f : 0.f);
        osum += v * v;
    }
#pragma unroll
    for (int msk = 8; msk >= 1; msk >>= 1) osum += __shfl_xor(osum, msk, 16);

    __shared__ float sp_s[B_GR], cl_s[B_GR], or_s[B_GR];
    if (k == 0) {
        sp_s[b] = tr / m2 - ds2 / (m2 * m2);
        cl_s[b] = sqrtf(cs2) / (float)npg * 4.0f - 1.0f;
        or_s[b] = sqrtf(osum);
    }
    __syncthreads();
    if (t == 0) {
        float a = 0.f, c = 0.f, o = 0.f;
        for (int i = 0; i < B_GR; ++i) { a += sp_s[i]; c += cl_s[i]; o += or_s[i]; }
        out[20480] = -a / 16.f;
        out[20481] = c / 16.f;
        out[20482] = o / 16.f;
    }

#pragma unroll
    for (int l = 0; l < 16; ++l) {
        float v = (l == k) ? 0.f : oar[l] / (dd * ddl[b * 16 + l]);
        out[16384 + b * 256 + k * 16 + l] = v;
    }
}

// ---------------------------------------------------------------------------
extern "C" void kernel_launch(void* const* d_in, const int* in_sizes, int n_in,
                              void* d_out, int out_size, void* d_ws, size_t ws_size,
                              hipStream_t stream)
{
    const float* x    = (const float*)d_in[0];
    const float* W    = (const float*)d_in[1];
    const float* bvec = (const float*)d_in[2];
    const float* ew   = (const float*)d_in[3];
    const int* erow   = (const int*)d_in[4];
    const int* ecol   = (const int*)d_in[5];

    int Ntot = in_sizes[0] / F_DIM;           // 131072
    size_t E = (size_t)in_sizes[3];           // 4194304
    int npg  = Ntot / B_GR;                   // 8192
    int edges_per_graph = (int)(E / B_GR);    // 262144
    int nmask = Ntot - 1;

    const int ADJ_BLOCKS  = 2048;             // 128 per graph, 8 per CU
    const int NODE_BLOCKS = 1024;             // 64 per graph, 4 per CU
    int adj_slots  = ADJ_BLOCKS / B_GR;       // 128
    int node_slots = NODE_BLOCKS / B_GR;      // 64
    int edges_per_block = (int)(E / ADJ_BLOCKS);          // 2048
    int npw = Ntot / (NODE_BLOCKS * 4);                   // 32

    char* ws = (char*)d_ws;
    size_t o = 0;
    float* ss    = (float*)(ws + o); o += (size_t)Ntot * 16 * 4;
    float* sraw  = (float*)(ws + o); o += (size_t)Ntot * 16 * 4;
    h16*   ssh   = (h16*)(ws + o);   o += (size_t)Ntot * 16 * 2;
    float* padj  = (float*)(ws + o); o += (size_t)ADJ_BLOCKS * 256 * 4;
    float* poutx = (float*)(ws + o); o += (size_t)NODE_BLOCKS * 1024 * 4;
    float* pCC   = (float*)(ws + o); o += (size_t)NODE_BLOCKS * 256 * 4;
    float* pcs   = (float*)(ws + o); o += (size_t)NODE_BLOCKS * 16 * 4;
    float* oadj  = (float*)(ws + o); o += (size_t)B_GR * 256 * 4;
    float* CCb   = (float*)(ws + o); o += (size_t)B_GR * 256 * 4;
    float* csb   = (float*)(ws + o); o += (size_t)B_GR * 16 * 4;

    k_assign<<<Ntot / 256, 256, 0, stream>>>(x, W, bvec, ss, sraw, ssh);
    k_edge<<<ADJ_BLOCKS, 256, 0, stream>>>(erow, ecol, ew, ssh, padj,
                                           edges_per_block, edges_per_graph, nmask);
    k_nodes<<<NODE_BLOCKS, 256, 0, stream>>>(x, sraw, ss, poutx, pCC, pcs, npw);
    k_reduce<<<B_GR, 256, 0, stream>>>(padj, poutx, pCC, pcs, oadj, CCb, csb,
                                       (float*)d_out, adj_slots, node_slots);
    k_final<<<1, 256, 0, stream>>>(oadj, CCb, csb, (float*)d_out, npg);
}

// Round 6
// 208.631 us; speedup vs baseline: 1.5914x; 1.5914x over previous
//
#include <hip/hip_runtime.h>
#include <math.h>

#define F_DIM 64
#define K_CL 16
#define B_GR 16

typedef _Float16 h16;
using f16x8 = __attribute__((ext_vector_type(8))) _Float16;
using f32x4 = __attribute__((ext_vector_type(4))) float;

// ---------------------------------------------------------------------------
// K1: s = x@W + b ; ss = softmax(s) (fp32 + f16 copy). One thread per node.
// ---------------------------------------------------------------------------
__global__ __launch_bounds__(256) void k_assign(
    const float* __restrict__ x, const float* __restrict__ W, const float* __restrict__ bvec,
    float* __restrict__ ss, float* __restrict__ sraw, h16* __restrict__ ssh)
{
    __shared__ float Wl[F_DIM * K_CL];
    __shared__ float bl[K_CL];
    int t = threadIdx.x;
    for (int idx = t; idx < F_DIM * K_CL; idx += 256) Wl[idx] = W[idx];
    if (t < K_CL) bl[t] = bvec[t];
    __syncthreads();

    size_t i = (size_t)blockIdx.x * 256 + t;
    float s[K_CL];
#pragma unroll
    for (int k = 0; k < 16; ++k) s[k] = bl[k];

    const float4* xp = reinterpret_cast<const float4*>(x + i * F_DIM);
#pragma unroll
    for (int j = 0; j < 16; ++j) {
        float4 q = xp[j];
        float xf[4] = {q.x, q.y, q.z, q.w};
#pragma unroll
        for (int ff = 0; ff < 4; ++ff) {
            int f = j * 4 + ff;
            float xv = xf[ff];
            const float4* wr = reinterpret_cast<const float4*>(&Wl[f * K_CL]);
            float4 w0 = wr[0], w1 = wr[1], w2 = wr[2], w3 = wr[3];
            s[0]  += xv * w0.x; s[1]  += xv * w0.y; s[2]  += xv * w0.z; s[3]  += xv * w0.w;
            s[4]  += xv * w1.x; s[5]  += xv * w1.y; s[6]  += xv * w1.z; s[7]  += xv * w1.w;
            s[8]  += xv * w2.x; s[9]  += xv * w2.y; s[10] += xv * w2.z; s[11] += xv * w2.w;
            s[12] += xv * w3.x; s[13] += xv * w3.y; s[14] += xv * w3.z; s[15] += xv * w3.w;
        }
    }

    float4* sp = reinterpret_cast<float4*>(sraw + i * K_CL);
    sp[0] = make_float4(s[0], s[1], s[2], s[3]);
    sp[1] = make_float4(s[4], s[5], s[6], s[7]);
    sp[2] = make_float4(s[8], s[9], s[10], s[11]);
    sp[3] = make_float4(s[12], s[13], s[14], s[15]);

    float m = s[0];
#pragma unroll
    for (int k = 1; k < 16; ++k) m = fmaxf(m, s[k]);
    float sum = 0.f;
#pragma unroll
    for (int k = 0; k < 16; ++k) { s[k] = __expf(s[k] - m); sum += s[k]; }
    float inv = 1.0f / sum;
#pragma unroll
    for (int k = 0; k < 16; ++k) s[k] *= inv;

    float4* qp = reinterpret_cast<float4*>(ss + i * K_CL);
    qp[0] = make_float4(s[0], s[1], s[2], s[3]);
    qp[1] = make_float4(s[4], s[5], s[6], s[7]);
    qp[2] = make_float4(s[8], s[9], s[10], s[11]);
    qp[3] = make_float4(s[12], s[13], s[14], s[15]);

    f16x8 h0, h1;
#pragma unroll
    for (int k = 0; k < 8; ++k) { h0[k] = (h16)s[k]; h1[k] = (h16)s[k + 8]; }
    f16x8* hp = reinterpret_cast<f16x8*>(ssh + i * K_CL);
    hp[0] = h0;
    hp[1] = h1;
}

// ---------------------------------------------------------------------------
// K2: oadj[k,l] = sum_e (w*ss[r,k])*ss[c,l] via MFMA 16x16x32_f16, K=edges.
// LDS-reduce then ONE global atomicAdd per thread into oadj (zeroed).
// ---------------------------------------------------------------------------
__global__ __launch_bounds__(256) void k_edge(
    const int* __restrict__ erow, const int* __restrict__ ecol, const float* __restrict__ ew,
    const h16* __restrict__ ssh, float* __restrict__ oadj,
    int edges_per_block, int edges_per_graph, int nmask)
{
    __shared__ float CCl[256];
    int t = threadIdx.x;
    CCl[t] = 0.f;
    __syncthreads();

    int bid = blockIdx.x;
    int xcd = bid & 7;
    int slot = bid >> 3;
    int graph = xcd + 8 * (slot & 1);
    int chunk = slot >> 1;

    int wid = t >> 6, lane = t & 63;
    int quad = lane >> 4, m = lane & 15;

    int epw = edges_per_block >> 2;
    size_t base = (size_t)graph * edges_per_graph
                + (size_t)chunk * edges_per_block
                + (size_t)wid * epw;

    f32x4 acc = {0.f, 0.f, 0.f, 0.f};

    for (int e0 = 0; e0 < epw; e0 += 64) {
        size_t eb = base + e0 + lane;
        int   rv = erow[eb] & nmask;
        int   cv = ecol[eb] & nmask;
        float wv = ew[eb];
#pragma unroll
        for (int h = 0; h < 2; ++h) {
            f16x8 afrag, bfrag;
#pragma unroll
            for (int j = 0; j < 8; ++j) {
                int src = h * 32 + quad * 8 + j;
                int   r = __shfl(rv, src, 64);
                int   c = __shfl(cv, src, 64);
                float w = __shfl(wv, src, 64);
                h16 av = ssh[(size_t)r * 16 + m];
                h16 bv = ssh[(size_t)c * 16 + m];
                afrag[j] = av * (h16)w;
                bfrag[j] = bv;
            }
            acc = __builtin_amdgcn_mfma_f32_16x16x32_f16(afrag, bfrag, acc, 0, 0, 0);
        }
    }

#pragma unroll
    for (int rg = 0; rg < 4; ++rg)
        atomicAdd(&CCl[(quad * 4 + rg) * 16 + m], acc[rg]);
    __syncthreads();
    atomicAdd(oadj + graph * 256 + t, CCl[t]);
}

// ---------------------------------------------------------------------------
// K3: per-node pass: outx[g,k,f], CC[g]=ss^T ss, cs[g,k]. Atomic tails.
// ---------------------------------------------------------------------------
__global__ __launch_bounds__(256) void k_nodes(
    const float* __restrict__ x, const float* __restrict__ sraw, const float* __restrict__ ss,
    float* __restrict__ outx, float* __restrict__ CCb, float* __restrict__ csb,
    int npw, int npg)
{
    __shared__ float redx[4 * K_CL * F_DIM];   // 16 KB
    __shared__ float CCl[256];
    __shared__ float csl[16];
    int t = threadIdx.x;
    CCl[t] = 0.f;
    if (t < 16) csl[t] = 0.f;
    __syncthreads();

    int wid = t >> 6, lane = t & 63;
    int g4 = lane >> 4, l = lane & 15;
    size_t base = ((size_t)blockIdx.x * 4 + wid) * npw;

    float accx[16];
#pragma unroll
    for (int k = 0; k < 16; ++k) accx[k] = 0.f;
    float accc[4] = {0.f, 0.f, 0.f, 0.f};
    float acccs = 0.f;

    for (int j = 0; j < npw; ++j) {
        size_t i = base + j;
        float xv = x[i * F_DIM + lane];
        const float4* sp = reinterpret_cast<const float4*>(sraw + i * K_CL);
        float4 s0 = sp[0], s1 = sp[1], s2 = sp[2], s3 = sp[3];
        accx[0]  += s0.x * xv; accx[1]  += s0.y * xv; accx[2]  += s0.z * xv; accx[3]  += s0.w * xv;
        accx[4]  += s1.x * xv; accx[5]  += s1.y * xv; accx[6]  += s1.z * xv; accx[7]  += s1.w * xv;
        accx[8]  += s2.x * xv; accx[9]  += s2.y * xv; accx[10] += s2.z * xv; accx[11] += s2.w * xv;
        accx[12] += s3.x * xv; accx[13] += s3.y * xv; accx[14] += s3.z * xv; accx[15] += s3.w * xv;

        float sv = ss[i * K_CL + l];
        accc[0] += __shfl(sv, g4 * 4 + 0, 16) * sv;
        accc[1] += __shfl(sv, g4 * 4 + 1, 16) * sv;
        accc[2] += __shfl(sv, g4 * 4 + 2, 16) * sv;
        accc[3] += __shfl(sv, g4 * 4 + 3, 16) * sv;
        acccs += sv;
    }

#pragma unroll
    for (int k = 0; k < 16; ++k) redx[wid * 1024 + k * 64 + lane] = accx[k];
#pragma unroll
    for (int j4 = 0; j4 < 4; ++j4)
        atomicAdd(&CCl[(g4 * 4 + j4) * 16 + l], accc[j4]);
    if (g4 == 0) atomicAdd(&csl[l], acccs);
    __syncthreads();

    int gb = (int)(base / (size_t)npg);
    float* dst = outx + gb * (K_CL * F_DIM);
#pragma unroll
    for (int it = 0; it < 4; ++it) {
        int idx = t + it * 256;
        float v = redx[idx] + redx[1024 + idx] + redx[2048 + idx] + redx[3072 + idx];
        atomicAdd(dst + idx, v);
    }
    atomicAdd(&CCb[gb * 256 + t], CCl[t]);
    if (t < 16) atomicAdd(&csb[gb * 16 + t], csl[t]);
}

// ---------------------------------------------------------------------------
// K4: grid 64. All blocks: parallel selu (1 elem/thread). Block 0: losses +
// out_adj_norm. dS = column sums of oadj, m2 = total sum.
// ---------------------------------------------------------------------------
__global__ __launch_bounds__(256) void k_final(
    const float* __restrict__ outx, const float* __restrict__ oadj,
    const float* __restrict__ CCb, const float* __restrict__ csb,
    float* __restrict__ out, int npg)
{
    int t = threadIdx.x;
    int gid = blockIdx.x * 256 + t;
    {
        float v = outx[gid];
        float r = (v > 0.f) ? (1.0507009873554805f * v)
                            : (1.0507009873554805f * 1.6732632423543772f * (__expf(v) - 1.0f));
        out[gid] = r;
    }

    if (blockIdx.x != 0) return;

    int b = t >> 4, k = t & 15;
    const float* oar = oadj + b * 256 + k * 16;
    const float* ccr = CCb + b * 256 + k * 16;

    float rowsum_off = 0.f, trace_c = 0.f, rowsum_all = 0.f, fro2 = 0.f, colsum = 0.f;
#pragma unroll
    for (int l = 0; l < 16; ++l) {
        float v = oar[l];
        rowsum_all += v;
        if (l == k) trace_c = v; else rowsum_off += v;
        float c = ccr[l];
        fro2 += c * c;
        colsum += oadj[b * 256 + l * 16 + k];
    }
    float dd = sqrtf(rowsum_off) + 1e-12f;
    __shared__ float ddl[B_GR * K_CL];
    ddl[t] = dd;

    float csv = csb[t];
    float ds2 = colsum * colsum, cs2 = csv * csv;
    float tr = trace_c, m2 = rowsum_all;
#pragma unroll
    for (int msk = 8; msk >= 1; msk >>= 1) {
        tr   += __shfl_xor(tr,   msk, 16);
        ds2  += __shfl_xor(ds2,  msk, 16);
        cs2  += __shfl_xor(cs2,  msk, 16);
        fro2 += __shfl_xor(fro2, msk, 16);
        m2   += __shfl_xor(m2,   msk, 16);
    }
    float invfro = 1.0f / sqrtf(fro2);
    float osum = 0.f;
#pragma unroll
    for (int l = 0; l < 16; ++l) {
        float v = ccr[l] * invfro - ((l == k) ? 0.25f : 0.f);
        osum += v * v;
    }
#pragma unroll
    for (int msk = 8; msk >= 1; msk >>= 1) osum += __shfl_xor(osum, msk, 16);

    __shared__ float sp_s[B_GR], cl_s[B_GR], or_s[B_GR];
    if (k == 0) {
        sp_s[b] = tr / m2 - ds2 / (m2 * m2);
        cl_s[b] = sqrtf(cs2) / (float)npg * 4.0f - 1.0f;
        or_s[b] = sqrtf(osum);
    }
    __syncthreads();
    if (t == 0) {
        float a = 0.f, c = 0.f, o = 0.f;
        for (int i = 0; i < B_GR; ++i) { a += sp_s[i]; c += cl_s[i]; o += or_s[i]; }
        out[20480] = -a / 16.f;
        out[20481] = c / 16.f;
        out[20482] = o / 16.f;
    }

#pragma unroll
    for (int l = 0; l < 16; ++l) {
        float v = (l == k) ? 0.f : oar[l] / (dd * ddl[b * 16 + l]);
        out[16384 + b * 256 + k * 16 + l] = v;
    }
}

// ---------------------------------------------------------------------------
extern "C" void kernel_launch(void* const* d_in, const int* in_sizes, int n_in,
                              void* d_out, int out_size, void* d_ws, size_t ws_size,
                              hipStream_t stream)
{
    const float* x    = (const float*)d_in[0];
    const float* W    = (const float*)d_in[1];
    const float* bvec = (const float*)d_in[2];
    const float* ew   = (const float*)d_in[3];
    const int* erow   = (const int*)d_in[4];
    const int* ecol   = (const int*)d_in[5];

    int Ntot = in_sizes[0] / F_DIM;           // 131072
    size_t E = (size_t)in_sizes[3];           // 4194304
    int npg  = Ntot / B_GR;                   // 8192
    int edges_per_graph = (int)(E / B_GR);    // 262144
    int nmask = Ntot - 1;

    const int ADJ_BLOCKS  = 2048;             // 128 per graph, 8 per CU
    const int NODE_BLOCKS = 1024;             // 64 per graph, 4 per CU
    int edges_per_block = (int)(E / ADJ_BLOCKS);          // 2048
    int npw = Ntot / (NODE_BLOCKS * 4);                   // 32

    char* ws = (char*)d_ws;
    size_t o = 0;
    float* ss    = (float*)(ws + o); o += (size_t)Ntot * 16 * 4;
    float* sraw  = (float*)(ws + o); o += (size_t)Ntot * 16 * 4;
    h16*   ssh   = (h16*)(ws + o);   o += (size_t)Ntot * 16 * 2;
    size_t zoff = o;
    float* outx  = (float*)(ws + o); o += (size_t)B_GR * 1024 * 4;
    float* oadj  = (float*)(ws + o); o += (size_t)B_GR * 256 * 4;
    float* CCb   = (float*)(ws + o); o += (size_t)B_GR * 256 * 4;
    float* csb   = (float*)(ws + o); o += (size_t)B_GR * 16 * 4;

    hipMemsetAsync(ws + zoff, 0, o - zoff, stream);

    k_assign<<<Ntot / 256, 256, 0, stream>>>(x, W, bvec, ss, sraw, ssh);
    k_edge<<<ADJ_BLOCKS, 256, 0, stream>>>(erow, ecol, ew, ssh, oadj,
                                           edges_per_block, edges_per_graph, nmask);
    k_nodes<<<NODE_BLOCKS, 256, 0, stream>>>(x, sraw, ss, outx, CCb, csb, npw, npg);
    k_final<<<64, 256, 0, stream>>>(outx, oadj, CCb, csb, (float*)d_out, npg);
}

// Round 7
// 169.861 us; speedup vs baseline: 1.9546x; 1.2282x over previous
//
#include <hip/hip_runtime.h>
#include <math.h>

#define F_DIM 64
#define K_CL 16
#define B_GR 16
#define SROW 72   // padded LDS row stride in f16 (144 B, 16B-multiple)

typedef _Float16 h16;
using f16x8 = __attribute__((ext_vector_type(8))) _Float16;
using f32x4 = __attribute__((ext_vector_type(4))) float;

// ---------------------------------------------------------------------------
// K1 (fused): s = x@W+b; softmax; write ssh (f16). Then per-wave LDS staging
// of sraw^T / ss^T / x^T and MFMA accumulation of outx (sraw^T x, 8 mfma)
// and CC (ss^T ss, 2 mfma). Block-reduce, global atomics.
// cluster_size is CC row-sums (softmax rows sum to 1) -> no cs array.
// ---------------------------------------------------------------------------
__global__ __launch_bounds__(256) void k_fused(
    const float* __restrict__ x, const float* __restrict__ W, const float* __restrict__ bvec,
    h16* __restrict__ ssh, float* __restrict__ outx, float* __restrict__ CCb)
{
    __shared__ float Wl[F_DIM * K_CL];
    __shared__ float bl[K_CL];
    __shared__ __align__(16) h16 stage[4][(16 + 16 + 64) * SROW];  // 55.3 KB

    int t = threadIdx.x;
    for (int idx = t; idx < F_DIM * K_CL; idx += 256) Wl[idx] = W[idx];
    if (t < K_CL) bl[t] = bvec[t];
    __syncthreads();

    int wid = t >> 6, lane = t & 63;
    h16* Sg = stage[wid];            // sraw^T  [16][SROW]
    h16* Cg = Sg + 16 * SROW;        // ss^T    [16][SROW]
    h16* Xg = Cg + 16 * SROW;        // x^T     [64][SROW]

    size_t i = (size_t)blockIdx.x * 256 + t;
    float s[16];
#pragma unroll
    for (int k = 0; k < 16; ++k) s[k] = bl[k];

    const float4* xp = reinterpret_cast<const float4*>(x + i * F_DIM);
#pragma unroll
    for (int j = 0; j < 16; ++j) {
        float4 q = xp[j];
        float xf[4] = {q.x, q.y, q.z, q.w};
#pragma unroll
        for (int ff = 0; ff < 4; ++ff) {
            int f = j * 4 + ff;
            float xv = xf[ff];
            Xg[f * SROW + lane] = (h16)xv;           // stage x^T
            const float4* wr = reinterpret_cast<const float4*>(&Wl[f * K_CL]);
            float4 w0 = wr[0], w1 = wr[1], w2 = wr[2], w3 = wr[3];
            s[0]  += xv * w0.x; s[1]  += xv * w0.y; s[2]  += xv * w0.z; s[3]  += xv * w0.w;
            s[4]  += xv * w1.x; s[5]  += xv * w1.y; s[6]  += xv * w1.z; s[7]  += xv * w1.w;
            s[8]  += xv * w2.x; s[9]  += xv * w2.y; s[10] += xv * w2.z; s[11] += xv * w2.w;
            s[12] += xv * w3.x; s[13] += xv * w3.y; s[14] += xv * w3.z; s[15] += xv * w3.w;
        }
    }

    // stage sraw^T
#pragma unroll
    for (int k = 0; k < 16; ++k) Sg[k * SROW + lane] = (h16)s[k];

    // softmax
    float m = s[0];
#pragma unroll
    for (int k = 1; k < 16; ++k) m = fmaxf(m, s[k]);
    float sum = 0.f;
#pragma unroll
    for (int k = 0; k < 16; ++k) { s[k] = __expf(s[k] - m); sum += s[k]; }
    float inv = 1.0f / sum;
#pragma unroll
    for (int k = 0; k < 16; ++k) s[k] *= inv;

    // stage ss^T + global ssh write
    f16x8 h0, h1;
#pragma unroll
    for (int k = 0; k < 8; ++k) { h0[k] = (h16)s[k]; h1[k] = (h16)s[k + 8]; }
#pragma unroll
    for (int k = 0; k < 8; ++k) {
        Cg[k * SROW + lane] = h0[k];
        Cg[(k + 8) * SROW + lane] = h1[k];
    }
    f16x8* hp = reinterpret_cast<f16x8*>(ssh + i * K_CL);
    hp[0] = h0;
    hp[1] = h1;

    // MFMA phase (wave-private LDS, no barrier needed)
    int q4 = lane >> 4, mm = lane & 15;
    f32x4 accO[4] = {{0.f,0.f,0.f,0.f},{0.f,0.f,0.f,0.f},{0.f,0.f,0.f,0.f},{0.f,0.f,0.f,0.f}};
    f32x4 accC = {0.f, 0.f, 0.f, 0.f};
#pragma unroll
    for (int h = 0; h < 2; ++h) {
        f16x8 aO = *(const f16x8*)&Sg[mm * SROW + h * 32 + q4 * 8];
        f16x8 aC = *(const f16x8*)&Cg[mm * SROW + h * 32 + q4 * 8];
        accC = __builtin_amdgcn_mfma_f32_16x16x32_f16(aC, aC, accC, 0, 0, 0);
#pragma unroll
        for (int ft = 0; ft < 4; ++ft) {
            f16x8 bO = *(const f16x8*)&Xg[(ft * 16 + mm) * SROW + h * 32 + q4 * 8];
            accO[ft] = __builtin_amdgcn_mfma_f32_16x16x32_f16(aO, bO, accO[ft], 0, 0, 0);
        }
    }
    __syncthreads();

    // block reduce (reuse staging LDS)
    float* redO = (float*)&stage[0][0];     // 4 x 1024
    float* redC = redO + 4096;              // 4 x 256
#pragma unroll
    for (int ft = 0; ft < 4; ++ft)
#pragma unroll
        for (int rg = 0; rg < 4; ++rg)
            redO[wid * 1024 + (q4 * 4 + rg) * 64 + ft * 16 + mm] = accO[ft][rg];
#pragma unroll
    for (int rg = 0; rg < 4; ++rg)
        redC[wid * 256 + (q4 * 4 + rg) * 16 + mm] = accC[rg];
    __syncthreads();

    int g = blockIdx.x >> 5;    // 32 blocks per graph
#pragma unroll
    for (int it = 0; it < 4; ++it) {
        int idx = t + it * 256;
        float v = redO[idx] + redO[1024 + idx] + redO[2048 + idx] + redO[3072 + idx];
        atomicAdd(outx + g * 1024 + idx, v);
    }
    {
        float v = redC[t] + redC[256 + t] + redC[512 + t] + redC[768 + t];
        atomicAdd(CCb + g * 256 + t, v);
    }
}

// ---------------------------------------------------------------------------
// K2: oadj via MFMA with LDS-transpose staging. Per 64 edges per wave:
// 3 coalesced edge loads + 4 dwordx4 ssh-row gathers, 32 ds_write_u16
// (transpose), 4 ds_read_b128 fragments, 2 MFMAs. No shfl.
// ---------------------------------------------------------------------------
__global__ __launch_bounds__(256) void k_edge(
    const int* __restrict__ erow, const int* __restrict__ ecol, const float* __restrict__ ew,
    const h16* __restrict__ ssh, float* __restrict__ oadj,
    int edges_per_block, int edges_per_graph, int nmask)
{
    __shared__ float CCl[256];
    __shared__ __align__(16) h16 stageE[4][32 * SROW];   // 18.4 KB
    int t = threadIdx.x;
    CCl[t] = 0.f;
    __syncthreads();

    int bid = blockIdx.x;
    int xcd = bid & 7;
    int slot = bid >> 3;
    int graph = xcd + 8 * (slot & 1);
    int chunk = slot >> 1;

    int wid = t >> 6, lane = t & 63;
    int q4 = lane >> 4, mm = lane & 15;
    h16* Ag = stageE[wid];
    h16* Bg = Ag + 16 * SROW;

    int epw = edges_per_block >> 2;
    size_t base = (size_t)graph * edges_per_graph
                + (size_t)chunk * edges_per_block
                + (size_t)wid * epw;

    const f16x8* sshp = reinterpret_cast<const f16x8*>(ssh);
    f32x4 acc = {0.f, 0.f, 0.f, 0.f};

    for (int e0 = 0; e0 < epw; e0 += 64) {
        size_t eb = base + e0 + lane;
        int   r = erow[eb] & nmask;
        int   c = ecol[eb] & nmask;
        float w = ew[eb];

        f16x8 a0 = sshp[2 * (size_t)r];
        f16x8 a1 = sshp[2 * (size_t)r + 1];
        f16x8 b0 = sshp[2 * (size_t)c];
        f16x8 b1 = sshp[2 * (size_t)c + 1];
        h16 wh = (h16)w;
#pragma unroll
        for (int k = 0; k < 8; ++k) { a0[k] *= wh; a1[k] *= wh; }

#pragma unroll
        for (int k = 0; k < 8; ++k) {
            Ag[k * SROW + lane]       = a0[k];
            Ag[(k + 8) * SROW + lane] = a1[k];
            Bg[k * SROW + lane]       = b0[k];
            Bg[(k + 8) * SROW + lane] = b1[k];
        }

#pragma unroll
        for (int h = 0; h < 2; ++h) {
            f16x8 af = *(const f16x8*)&Ag[mm * SROW + h * 32 + q4 * 8];
            f16x8 bf = *(const f16x8*)&Bg[mm * SROW + h * 32 + q4 * 8];
            acc = __builtin_amdgcn_mfma_f32_16x16x32_f16(af, bf, acc, 0, 0, 0);
        }
    }

#pragma unroll
    for (int rg = 0; rg < 4; ++rg)
        atomicAdd(&CCl[(q4 * 4 + rg) * 16 + mm], acc[rg]);
    __syncthreads();
    atomicAdd(oadj + graph * 256 + t, CCl[t]);
}

// ---------------------------------------------------------------------------
// K3: grid 64. All blocks: parallel selu. Block 0: losses + out_adj_norm.
// dS = column sums of oadj, m2 = total sum, cs = row sums of CC.
// ---------------------------------------------------------------------------
__global__ __launch_bounds__(256) void k_final(
    const float* __restrict__ outx, const float* __restrict__ oadj,
    const float* __restrict__ CCb, float* __restrict__ out, int npg)
{
    int t = threadIdx.x;
    int gid = blockIdx.x * 256 + t;
    {
        float v = outx[gid];
        float r = (v > 0.f) ? (1.0507009873554805f * v)
                            : (1.0507009873554805f * 1.6732632423543772f * (__expf(v) - 1.0f));
        out[gid] = r;
    }

    if (blockIdx.x != 0) return;

    int b = t >> 4, k = t & 15;
    const float* oar = oadj + b * 256 + k * 16;
    const float* ccr = CCb + b * 256 + k * 16;

    float rowsum_off = 0.f, trace_c = 0.f, rowsum_all = 0.f, fro2 = 0.f, colsum = 0.f;
    float csv = 0.f;
#pragma unroll
    for (int l = 0; l < 16; ++l) {
        float v = oar[l];
        rowsum_all += v;
        if (l == k) trace_c = v; else rowsum_off += v;
        float c = ccr[l];
        fro2 += c * c;
        csv += c;                              // cluster_size[k] = sum_l CC[k][l]
        colsum += oadj[b * 256 + l * 16 + k];
    }
    float dd = sqrtf(rowsum_off) + 1e-12f;
    __shared__ float ddl[B_GR * K_CL];
    ddl[t] = dd;

    float ds2 = colsum * colsum, cs2 = csv * csv;
    float tr = trace_c, m2 = rowsum_all;
#pragma unroll
    for (int msk = 8; msk >= 1; msk >>= 1) {
        tr   += __shfl_xor(tr,   msk, 16);
        ds2  += __shfl_xor(ds2,  msk, 16);
        cs2  += __shfl_xor(cs2,  msk, 16);
        fro2 += __shfl_xor(fro2, msk, 16);
        m2   += __shfl_xor(m2,   msk, 16);
    }
    float invfro = 1.0f / sqrtf(fro2);
    float osum = 0.f;
#pragma unroll
    for (int l = 0; l < 16; ++l) {
        float v = ccr[l] * invfro - ((l == k) ? 0.25f : 0.f);
        osum += v * v;
    }
#pragma unroll
    for (int msk = 8; msk >= 1; msk >>= 1) osum += __shfl_xor(osum, msk, 16);

    __shared__ float sp_s[B_GR], cl_s[B_GR], or_s[B_GR];
    if (k == 0) {
        sp_s[b] = tr / m2 - ds2 / (m2 * m2);
        cl_s[b] = sqrtf(cs2) / (float)npg * 4.0f - 1.0f;
        or_s[b] = sqrtf(osum);
    }
    __syncthreads();
    if (t == 0) {
        float a = 0.f, c = 0.f, o = 0.f;
        for (int i = 0; i < B_GR; ++i) { a += sp_s[i]; c += cl_s[i]; o += or_s[i]; }
        out[20480] = -a / 16.f;
        out[20481] = c / 16.f;
        out[20482] = o / 16.f;
    }

#pragma unroll
    for (int l = 0; l < 16; ++l) {
        float v = (l == k) ? 0.f : oar[l] / (dd * ddl[b * 16 + l]);
        out[16384 + b * 256 + k * 16 + l] = v;
    }
}

// ---------------------------------------------------------------------------
extern "C" void kernel_launch(void* const* d_in, const int* in_sizes, int n_in,
                              void* d_out, int out_size, void* d_ws, size_t ws_size,
                              hipStream_t stream)
{
    const float* x    = (const float*)d_in[0];
    const float* W    = (const float*)d_in[1];
    const float* bvec = (const float*)d_in[2];
    const float* ew   = (const float*)d_in[3];
    const int* erow   = (const int*)d_in[4];
    const int* ecol   = (const int*)d_in[5];

    int Ntot = in_sizes[0] / F_DIM;           // 131072
    size_t E = (size_t)in_sizes[3];           // 4194304
    int npg  = Ntot / B_GR;                   // 8192
    int edges_per_graph = (int)(E / B_GR);    // 262144
    int nmask = Ntot - 1;

    const int ADJ_BLOCKS = 2048;              // 128 per graph, 8 per CU
    int edges_per_block = (int)(E / ADJ_BLOCKS);          // 2048

    char* ws = (char*)d_ws;
    size_t o = 0;
    h16*   ssh   = (h16*)(ws + o);   o += (size_t)Ntot * 16 * 2;
    size_t zoff = o;
    float* outx  = (float*)(ws + o); o += (size_t)B_GR * 1024 * 4;
    float* oadj  = (float*)(ws + o); o += (size_t)B_GR * 256 * 4;
    float* CCb   = (float*)(ws + o); o += (size_t)B_GR * 256 * 4;

    hipMemsetAsync(ws + zoff, 0, o - zoff, stream);

    k_fused<<<Ntot / 256, 256, 0, stream>>>(x, W, bvec, ssh, outx, CCb);
    k_edge<<<ADJ_BLOCKS, 256, 0, stream>>>(erow, ecol, ew, ssh, oadj,
                                           edges_per_block, edges_per_graph, nmask);
    k_final<<<64, 256, 0, stream>>>(outx, oadj, CCb, (float*)d_out, npg);
}